// Round 12
// baseline (418.306 us; speedup 1.0000x reference)
//
#include <hip/hip_runtime.h>

typedef unsigned short u16;
typedef unsigned int u32;
typedef __bf16 bf16x8 __attribute__((ext_vector_type(8)));
typedef float f32x4 __attribute__((ext_vector_type(4)));
typedef u16 u16x4 __attribute__((ext_vector_type(4)));
typedef u16 u16x8 __attribute__((ext_vector_type(8)));

#define MFMA16x16x32(a, b, c) __builtin_amdgcn_mfma_f32_16x16x32_bf16((a), (b), (c), 0, 0, 0)

static constexpr int kB = 4;
static constexpr int kC = 256;
static constexpr int kN = 4096;     // H*W
static constexpr int kHeads = 4;    // per batch
static constexpr int kD = 64;       // head dim
static constexpr int kSplit = 4;
static constexpr float kScale = 0.35355339059327373f;  // 64^-0.25

__device__ __forceinline__ u16 f2bf(float f) {
  union { float f; u32 i; } v; v.f = f;
  return (u16)((v.i + 0x7fffu + ((v.i >> 16) & 1u)) >> 16);
}
__device__ __forceinline__ bf16x8 ldb8(const u16* p) {
  return *reinterpret_cast<const bf16x8*>(p);
}

// ---------------------------------------------------------------------------
// fp32 -> bf16 weight conversion (grid-stride).
// ---------------------------------------------------------------------------
__global__ void convert_bf16(const float* __restrict__ in, u16* __restrict__ out,
                             int n) {
  for (int i = blockIdx.x * blockDim.x + threadIdx.x; i < n;
       i += gridDim.x * blockDim.x)
    out[i] = f2bf(in[i]);
}

// ---------------------------------------------------------------------------
// GroupNorm (validated r4). Writes bf16 transposed xnT[b][t][c].
// ---------------------------------------------------------------------------
__global__ __launch_bounds__(1024) void gn_kernel(const float* __restrict__ x,
                                                  const float* __restrict__ gnw,
                                                  const float* __restrict__ gnb,
                                                  u16* __restrict__ xnT) {
  const int g = blockIdx.x, b = blockIdx.y;
  const int tid = threadIdx.x;
  const float* xb = x + b * (kC * kN) + g * 8 * kN;
  float vals[4][8];
  float s = 0.f, ss = 0.f;
#pragma unroll
  for (int kk = 0; kk < 4; ++kk) {
    const int t = tid + kk * 1024;
#pragma unroll
    for (int c = 0; c < 8; ++c) {
      const float v_ = xb[c * kN + t];
      vals[kk][c] = v_;
      s += v_; ss += v_ * v_;
    }
  }
#pragma unroll
  for (int off = 32; off > 0; off >>= 1) {
    s += __shfl_down(s, off);
    ss += __shfl_down(ss, off);
  }
  __shared__ float rbuf[32];
  const int wid = tid >> 6, lane = tid & 63;
  if (lane == 0) { rbuf[wid] = s; rbuf[16 + wid] = ss; }
  __syncthreads();
  if (tid < 64) {
    float s2 = (lane < 16) ? rbuf[lane] : 0.f;
    float ss2 = (lane < 16) ? rbuf[16 + lane] : 0.f;
#pragma unroll
    for (int off = 8; off > 0; off >>= 1) {
      s2 += __shfl_down(s2, off);
      ss2 += __shfl_down(ss2, off);
    }
    if (lane == 0) { rbuf[0] = s2; rbuf[1] = ss2; }
  }
  __syncthreads();
  const float inv_n = 1.f / 32768.f;
  const float mu = rbuf[0] * inv_n;
  const float var = rbuf[1] * inv_n - mu * mu;
  const float rs = rsqrtf(var + 1e-5f);
  float wv[8], bv[8];
#pragma unroll
  for (int c = 0; c < 8; ++c) {
    const float wgt = gnw[g * 8 + c] * rs;
    wv[c] = wgt;
    bv[c] = gnb[g * 8 + c] - mu * wgt;
  }
  u16* ob = xnT + b * (kN * kC) + g * 8;
#pragma unroll
  for (int kk = 0; kk < 4; ++kk) {
    const int t = tid + kk * 1024;
    u16x8 pk;
#pragma unroll
    for (int c = 0; c < 8; ++c) pk[c] = f2bf(vals[kk][c] * wv[c] + bv[c]);
    *reinterpret_cast<u16x8*>(ob + t * kC) = pk;
  }
}

// ---------------------------------------------------------------------------
// QKV GEMM (validated r4). Epilogue: qT/kT[bh][t][64] pre-scaled, v[bh][64][s].
// ---------------------------------------------------------------------------
__global__ __launch_bounds__(256) void qkv_gemm(const u16* __restrict__ qkvw,
                                                const float* __restrict__ qkvb,
                                                const u16* __restrict__ xnT,
                                                u16* __restrict__ qt,
                                                u16* __restrict__ kt,
                                                u16* __restrict__ vv) {
  const int nblk = blockIdx.x, mblk = blockIdx.y, b = blockIdx.z;
  const int tid = threadIdx.x;
  const int w = tid >> 6, l = tid & 63, quad = l >> 4, col = l & 15;
  const int m0 = mblk * 64 + w * 16;
  const int n0 = nblk * 64;
  const u16* xb = xnT + b * (kN * kC);
  f32x4 acc[4] = {{0,0,0,0},{0,0,0,0},{0,0,0,0},{0,0,0,0}};
  const u16* ap = qkvw + (m0 + col) * kC + quad * 8;
  const u16* bp = xb + (n0 + col) * kC + quad * 8;
#pragma unroll
  for (int ks = 0; ks < 8; ++ks) {
    const bf16x8 af = ldb8(ap + ks * 32);
#pragma unroll
    for (int nt = 0; nt < 4; ++nt) {
      const bf16x8 bfr = ldb8(bp + nt * (16 * kC) + ks * 32);
      acc[nt] = MFMA16x16x32(af, bfr, acc[nt]);
    }
  }
  const int o_base = m0 + quad * 4;
  const int head = o_base / 192;
  const int rr = o_base % 192;
  const int bh = b * kHeads + head;
  const int seg = rr >> 6;
  const int c0 = rr & 63;
  float bias[4];
#pragma unroll
  for (int r = 0; r < 4; ++r) bias[r] = qkvb[o_base + r];
#pragma unroll
  for (int nt = 0; nt < 4; ++nt) {
    const int t = n0 + nt * 16 + col;
    if (seg == 2) {
#pragma unroll
      for (int r = 0; r < 4; ++r)
        vv[bh * (kD * kN) + (c0 + r) * kN + t] = f2bf(acc[nt][r] + bias[r]);
    } else {
      u16* dst = (seg == 0 ? qt : kt) + bh * (kN * kD) + t * kD + c0;
      u16x4 pk;
#pragma unroll
      for (int r = 0; r < 4; ++r) pk[r] = f2bf((acc[nt][r] + bias[r]) * kScale);
      *reinterpret_cast<u16x4*>(dst) = pk;
    }
  }
}

// ---------------------------------------------------------------------------
// Flash attention, linear split form, 32 Q-rows/wave, kSplit=4.
// r12: K software-pipelined one iteration ahead (two K reg buffers, manual
// 2x unroll). In-order issue previously exposed full K L2 latency per iter
// (r9/r11 invariant: 593 cyc/iter vs ~300 issue). V keeps intra-iteration
// coverage. launch_bounds(256,4): ~120 regs incl acc fits 4 waves/SIMD.
// ---------------------------------------------------------------------------
__global__ __launch_bounds__(256, 4) void attn_split(const u16* __restrict__ qt,
                                                     const u16* __restrict__ kt,
                                                     const u16* __restrict__ vv,
                                                     float* __restrict__ pO,
                                                     float* __restrict__ pl) {
  const int tblk = blockIdx.x, bh = blockIdx.y, z = blockIdx.z;
  const int tid = threadIdx.x;
  const int w = tid >> 6, l = tid & 63, quad = l >> 4, col = l & 15;
  const int t0 = tblk * 128 + w * 32;
  const u16* qb = qt + bh * (kN * kD);
  const u16* kb = kt + bh * (kN * kD);
  const u16* vb = vv + bh * (kD * kN);
  bf16x8 qf[2][2];
#pragma unroll
  for (int i = 0; i < 2; ++i) {
    qf[i][0] = ldb8(qb + (t0 + i * 16 + col) * kD + quad * 8);
    qf[i][1] = ldb8(qb + (t0 + i * 16 + col) * kD + 32 + quad * 8);
  }
  u16x8 ones_u;
#pragma unroll
  for (int i = 0; i < 8; ++i) ones_u[i] = 0x3f80;  // bf16 1.0
  const bf16x8 onesf = *reinterpret_cast<bf16x8*>(&ones_u);
  f32x4 oacc[2][4] = {{{0,0,0,0},{0,0,0,0},{0,0,0,0},{0,0,0,0}},
                      {{0,0,0,0},{0,0,0,0},{0,0,0,0},{0,0,0,0}}};
  f32x4 lacc[2] = {{0,0,0,0},{0,0,0,0}};
  __shared__ __align__(16) u16 pbuf[2][4][2][16][36];  // parity-double-buffered P
  const int s_beg = z * (kN / kSplit);

#define LOAD_K(s0, kk)                                   \
  {                                                      \
    const u16* kr_ = kb + (s0)*kD + quad * 8;            \
    kk[0] = ldb8(kr_ + col * kD);                        \
    kk[1] = ldb8(kr_ + col * kD + 32);                   \
    kk[2] = ldb8(kr_ + (col + 16) * kD);                 \
    kk[3] = ldb8(kr_ + (col + 16) * kD + 32);            \
  }

#define STEP(s0, kk, kn, snext, par)                                          \
  {                                                                           \
    const u16* vr_ = vb + (s0) + quad * 8;                                    \
    bf16x8 vf[4];                                                             \
    _Pragma("unroll") for (int ct = 0; ct < 4; ++ct)                          \
        vf[ct] = ldb8(vr_ + (ct * 16 + col) * kN);                            \
    LOAD_K(snext, kn);  /* prefetch next-iter K into alternate buffer */      \
    u16(*pw)[16][36] = pbuf[par][w];                                          \
    _Pragma("unroll") for (int i = 0; i < 2; ++i) {                           \
      f32x4 sa0 = {0, 0, 0, 0}, sa1 = {0, 0, 0, 0};                           \
      sa0 = MFMA16x16x32(qf[i][0], kk[0], sa0);                               \
      sa0 = MFMA16x16x32(qf[i][1], kk[1], sa0);                               \
      sa1 = MFMA16x16x32(qf[i][0], kk[2], sa1);                               \
      sa1 = MFMA16x16x32(qf[i][1], kk[3], sa1);                               \
      _Pragma("unroll") for (int r = 0; r < 4; ++r) {                         \
        pw[i][quad * 4 + r][col] = f2bf(__expf(sa0[r]));                      \
        pw[i][quad * 4 + r][col + 16] = f2bf(__expf(sa1[r]));                 \
      }                                                                       \
    }                                                                         \
    asm volatile("s_waitcnt lgkmcnt(0)" ::: "memory");                        \
    const bf16x8 pf0 = ldb8(&pw[0][col][quad * 8]);                           \
    const bf16x8 pf1 = ldb8(&pw[1][col][quad * 8]);                           \
    _Pragma("unroll") for (int ct = 0; ct < 4; ++ct) {                        \
      oacc[0][ct] = MFMA16x16x32(pf0, vf[ct], oacc[0][ct]);                   \
      oacc[1][ct] = MFMA16x16x32(pf1, vf[ct], oacc[1][ct]);                   \
    }                                                                         \
    lacc[0] = MFMA16x16x32(pf0, onesf, lacc[0]);                              \
    lacc[1] = MFMA16x16x32(pf1, onesf, lacc[1]);                              \
  }

  bf16x8 ka[4], kbuf[4];
  LOAD_K(s_beg, ka);
  for (int ii = 0; ii < kN / kSplit; ii += 64) {
    const int s0 = s_beg + ii;
    STEP(s0, ka, kbuf, s0 + 32, 0);
    // last prefetch wraps to s_beg (valid memory, result unused) — no branch
    const int snext = (ii + 64 < kN / kSplit) ? s0 + 64 : s_beg;
    STEP(s0 + 32, kbuf, ka, snext, 1);
  }
#undef STEP
#undef LOAD_K

  float* po = pO + (size_t)(z * 16 + bh) * kN * kD;
  float* plp = pl + (size_t)(z * 16 + bh) * kN;
#pragma unroll
  for (int i = 0; i < 2; ++i)
#pragma unroll
    for (int r = 0; r < 4; ++r) {
      const int t = t0 + i * 16 + quad * 4 + r;
#pragma unroll
      for (int ct = 0; ct < 4; ++ct)
        po[(size_t)t * kD + ct * 16 + col] = oacc[i][ct][r];
      if (col == 0) plp[t] = lacc[i][r];
    }
}

// ---------------------------------------------------------------------------
// Combine 4 split partials: O = sum_z O_z / sum_z l_z -> ht[b][t][c] bf16.
// ---------------------------------------------------------------------------
__global__ __launch_bounds__(256) void attn_combine(const float* __restrict__ pO,
                                                    const float* __restrict__ pl,
                                                    u16* __restrict__ ht) {
  const int idx = blockIdx.x * 256 + threadIdx.x;   // 16bh * 4096t * 16chunks
  const int c0 = (idx & 15) * 4;
  const int t = (idx >> 4) & (kN - 1);
  const int bh = idx >> 16;
  f32x4 acc = {0, 0, 0, 0};
  float lsum = 0.f;
#pragma unroll
  for (int z = 0; z < kSplit; ++z) {
    const size_t base = ((size_t)(z * 16 + bh) * kN + t);
    acc += *reinterpret_cast<const f32x4*>(pO + base * kD + c0);
    lsum += pl[base];
  }
  const float inv = 1.f / lsum;
  u16x4 pk;
#pragma unroll
  for (int i = 0; i < 4; ++i) pk[i] = f2bf(acc[i] * inv);
  const int b = bh >> 2, head = bh & 3;
  *reinterpret_cast<u16x4*>(ht + (size_t)b * (kN * kC) + (size_t)t * kC +
                            head * kD + c0) = pk;
}

// ---------------------------------------------------------------------------
// Proj GEMM + bias + residual: out fp32 (B,C,H,W). Validated r6.
// ---------------------------------------------------------------------------
__global__ __launch_bounds__(256) void proj_kernel(const u16* __restrict__ projw,
                                                   const float* __restrict__ projb,
                                                   const u16* __restrict__ ht,
                                                   const float* __restrict__ x,
                                                   float* __restrict__ out) {
  const int nblk = blockIdx.x, mblk = blockIdx.y, b = blockIdx.z;
  const int tid = threadIdx.x;
  const int w = tid >> 6, l = tid & 63, quad = l >> 4, col = l & 15;
  const int m0 = mblk * 64 + w * 16;
  const int n0 = nblk * 64;
  const u16* hb = ht + b * (kN * kC);
  f32x4 acc[4] = {{0,0,0,0},{0,0,0,0},{0,0,0,0},{0,0,0,0}};
  const u16* ap = projw + (m0 + col) * kC + quad * 8;
  const u16* bp = hb + (n0 + col) * kC + quad * 8;
#pragma unroll
  for (int ks = 0; ks < 8; ++ks) {
    const bf16x8 af = ldb8(ap + ks * 32);
#pragma unroll
    for (int nt = 0; nt < 4; ++nt) {
      const bf16x8 bfr = ldb8(bp + nt * (16 * kC) + ks * 32);
      acc[nt] = MFMA16x16x32(af, bfr, acc[nt]);
    }
  }
#pragma unroll
  for (int nt = 0; nt < 4; ++nt) {
    const int t = n0 + nt * 16 + col;
#pragma unroll
    for (int r = 0; r < 4; ++r) {
      const int o = m0 + quad * 4 + r;
      const int idx = b * (kC * kN) + o * kN + t;
      out[idx] = acc[nt][r] + projb[o] + x[idx];
    }
  }
}

extern "C" void kernel_launch(void* const* d_in, const int* in_sizes, int n_in,
                              void* d_out, int out_size, void* d_ws, size_t ws_size,
                              hipStream_t stream) {
  const float* x = (const float*)d_in[0];
  const float* gnw = (const float*)d_in[1];
  const float* gnb = (const float*)d_in[2];
  const float* qkvw_f = (const float*)d_in[3];
  const float* qkvb = (const float*)d_in[4];
  const float* projw_f = (const float*)d_in[5];
  const float* projb = (const float*)d_in[6];
  float* out = (float*)d_out;

  char* ws = (char*)d_ws;
  u16* xnT = (u16*)(ws);                      // 8 MiB
  u16* qt = (u16*)(ws + (8u << 20));          // 8 MiB
  u16* kt = (u16*)(ws + (16u << 20));         // 8 MiB
  u16* vv = (u16*)(ws + (24u << 20));         // 8 MiB
  u16* ht = (u16*)(ws + (32u << 20));         // 8 MiB
  u16* qkvw = (u16*)(ws + (40u << 20));       // 384 KiB
  u16* projw = (u16*)(ws + (41u << 20));      // 128 KiB
  float* pO = (float*)(ws + (48u << 20));     // 64 MiB (4 splits)
  float* pl = (float*)(ws + (112u << 20));    // 1 MiB

  convert_bf16<<<dim3(192), dim3(256), 0, stream>>>(qkvw_f, qkvw, 768 * kC);
  convert_bf16<<<dim3(64), dim3(256), 0, stream>>>(projw_f, projw, kC * kC);
  gn_kernel<<<dim3(32, 4), dim3(1024), 0, stream>>>(x, gnw, gnb, xnT);
  qkv_gemm<<<dim3(64, 12, 4), dim3(256), 0, stream>>>(qkvw, qkvb, xnT, qt, kt, vv);
  attn_split<<<dim3(32, 16, kSplit), dim3(256), 0, stream>>>(qt, kt, vv, pO, pl);
  attn_combine<<<dim3(4096), dim3(256), 0, stream>>>(pO, pl, ht);
  proj_kernel<<<dim3(64, 4, 4), dim3(256), 0, stream>>>(projw, projb, ht, x, out);
}

// Round 13
// 325.272 us; speedup vs baseline: 1.2860x; 1.2860x over previous
//
#include <hip/hip_runtime.h>

typedef unsigned short u16;
typedef unsigned int u32;
typedef __bf16 bf16x8 __attribute__((ext_vector_type(8)));
typedef float f32x4 __attribute__((ext_vector_type(4)));
typedef u16 u16x4 __attribute__((ext_vector_type(4)));
typedef u16 u16x8 __attribute__((ext_vector_type(8)));

#define MFMA16x16x32(a, b, c) __builtin_amdgcn_mfma_f32_16x16x32_bf16((a), (b), (c), 0, 0, 0)

static constexpr int kB = 4;
static constexpr int kC = 256;
static constexpr int kN = 4096;     // H*W
static constexpr int kHeads = 4;    // per batch
static constexpr int kD = 64;       // head dim
static constexpr int kSplit = 8;    // s-range split (2048 blocks, smooth batching)
static constexpr float kScale = 0.35355339059327373f;  // 64^-0.25

__device__ __forceinline__ u16 f2bf(float f) {
  union { float f; u32 i; } v; v.f = f;
  return (u16)((v.i + 0x7fffu + ((v.i >> 16) & 1u)) >> 16);
}
__device__ __forceinline__ bf16x8 ldb8(const u16* p) {
  return *reinterpret_cast<const bf16x8*>(p);
}

// ---------------------------------------------------------------------------
// fp32 -> bf16 weight conversion (grid-stride).
// ---------------------------------------------------------------------------
__global__ void convert_bf16(const float* __restrict__ in, u16* __restrict__ out,
                             int n) {
  for (int i = blockIdx.x * blockDim.x + threadIdx.x; i < n;
       i += gridDim.x * blockDim.x)
    out[i] = f2bf(in[i]);
}

// ---------------------------------------------------------------------------
// GroupNorm (validated r4). Writes bf16 transposed xnT[b][t][c].
// ---------------------------------------------------------------------------
__global__ __launch_bounds__(1024) void gn_kernel(const float* __restrict__ x,
                                                  const float* __restrict__ gnw,
                                                  const float* __restrict__ gnb,
                                                  u16* __restrict__ xnT) {
  const int g = blockIdx.x, b = blockIdx.y;
  const int tid = threadIdx.x;
  const float* xb = x + b * (kC * kN) + g * 8 * kN;
  float vals[4][8];
  float s = 0.f, ss = 0.f;
#pragma unroll
  for (int kk = 0; kk < 4; ++kk) {
    const int t = tid + kk * 1024;
#pragma unroll
    for (int c = 0; c < 8; ++c) {
      const float v_ = xb[c * kN + t];
      vals[kk][c] = v_;
      s += v_; ss += v_ * v_;
    }
  }
#pragma unroll
  for (int off = 32; off > 0; off >>= 1) {
    s += __shfl_down(s, off);
    ss += __shfl_down(ss, off);
  }
  __shared__ float rbuf[32];
  const int wid = tid >> 6, lane = tid & 63;
  if (lane == 0) { rbuf[wid] = s; rbuf[16 + wid] = ss; }
  __syncthreads();
  if (tid < 64) {
    float s2 = (lane < 16) ? rbuf[lane] : 0.f;
    float ss2 = (lane < 16) ? rbuf[16 + lane] : 0.f;
#pragma unroll
    for (int off = 8; off > 0; off >>= 1) {
      s2 += __shfl_down(s2, off);
      ss2 += __shfl_down(ss2, off);
    }
    if (lane == 0) { rbuf[0] = s2; rbuf[1] = ss2; }
  }
  __syncthreads();
  const float inv_n = 1.f / 32768.f;
  const float mu = rbuf[0] * inv_n;
  const float var = rbuf[1] * inv_n - mu * mu;
  const float rs = rsqrtf(var + 1e-5f);
  float wv[8], bv[8];
#pragma unroll
  for (int c = 0; c < 8; ++c) {
    const float wgt = gnw[g * 8 + c] * rs;
    wv[c] = wgt;
    bv[c] = gnb[g * 8 + c] - mu * wgt;
  }
  u16* ob = xnT + b * (kN * kC) + g * 8;
#pragma unroll
  for (int kk = 0; kk < 4; ++kk) {
    const int t = tid + kk * 1024;
    u16x8 pk;
#pragma unroll
    for (int c = 0; c < 8; ++c) pk[c] = f2bf(vals[kk][c] * wv[c] + bv[c]);
    *reinterpret_cast<u16x8*>(ob + t * kC) = pk;
  }
}

// ---------------------------------------------------------------------------
// QKV GEMM (validated r4). Epilogue: qT/kT[bh][t][64] pre-scaled, v[bh][64][s].
// ---------------------------------------------------------------------------
__global__ __launch_bounds__(256) void qkv_gemm(const u16* __restrict__ qkvw,
                                                const float* __restrict__ qkvb,
                                                const u16* __restrict__ xnT,
                                                u16* __restrict__ qt,
                                                u16* __restrict__ kt,
                                                u16* __restrict__ vv) {
  const int nblk = blockIdx.x, mblk = blockIdx.y, b = blockIdx.z;
  const int tid = threadIdx.x;
  const int w = tid >> 6, l = tid & 63, quad = l >> 4, col = l & 15;
  const int m0 = mblk * 64 + w * 16;
  const int n0 = nblk * 64;
  const u16* xb = xnT + b * (kN * kC);
  f32x4 acc[4] = {{0,0,0,0},{0,0,0,0},{0,0,0,0},{0,0,0,0}};
  const u16* ap = qkvw + (m0 + col) * kC + quad * 8;
  const u16* bp = xb + (n0 + col) * kC + quad * 8;
#pragma unroll
  for (int ks = 0; ks < 8; ++ks) {
    const bf16x8 af = ldb8(ap + ks * 32);
#pragma unroll
    for (int nt = 0; nt < 4; ++nt) {
      const bf16x8 bfr = ldb8(bp + nt * (16 * kC) + ks * 32);
      acc[nt] = MFMA16x16x32(af, bfr, acc[nt]);
    }
  }
  const int o_base = m0 + quad * 4;
  const int head = o_base / 192;
  const int rr = o_base % 192;
  const int bh = b * kHeads + head;
  const int seg = rr >> 6;
  const int c0 = rr & 63;
  float bias[4];
#pragma unroll
  for (int r = 0; r < 4; ++r) bias[r] = qkvb[o_base + r];
#pragma unroll
  for (int nt = 0; nt < 4; ++nt) {
    const int t = n0 + nt * 16 + col;
    if (seg == 2) {
#pragma unroll
      for (int r = 0; r < 4; ++r)
        vv[bh * (kD * kN) + (c0 + r) * kN + t] = f2bf(acc[nt][r] + bias[r]);
    } else {
      u16* dst = (seg == 0 ? qt : kt) + bh * (kN * kD) + t * kD + c0;
      u16x4 pk;
#pragma unroll
      for (int r = 0; r < 4; ++r) pk[r] = f2bf((acc[nt][r] + bias[r]) * kScale);
      *reinterpret_cast<u16x4*>(dst) = pk;
    }
  }
}

// ---------------------------------------------------------------------------
// Flash attention, linear split form. r13: 64 Q-rows per wave (4 Q-tiles).
// Empirical law from r7-r12: time = #wave-iterations x ~600 cyc, invariant
// to VALU/prefetch/occupancy; each iteration = 8 global fragment loads.
// 4 tiles share each K/V load -> wave-iterations halve vs r11.
// launch_bounds(256,2): ~170 unified regs (64 oacc + 16 lacc AGPR + ~85
// arch) must NOT spill (r10 lesson) - 256-reg budget guarantees that.
// ---------------------------------------------------------------------------
__global__ __launch_bounds__(256, 2) void attn_split(const u16* __restrict__ qt,
                                                     const u16* __restrict__ kt,
                                                     const u16* __restrict__ vv,
                                                     float* __restrict__ pO,
                                                     float* __restrict__ pl) {
  const int tblk = blockIdx.x, bh = blockIdx.y, z = blockIdx.z;
  const int tid = threadIdx.x;
  const int w = tid >> 6, l = tid & 63, quad = l >> 4, col = l & 15;
  const int t0 = tblk * 256 + w * 64;
  const u16* qb = qt + bh * (kN * kD);
  const u16* kb = kt + bh * (kN * kD);
  const u16* vb = vv + bh * (kD * kN);
  bf16x8 qf[4][2];
#pragma unroll
  for (int ti = 0; ti < 4; ++ti) {
    qf[ti][0] = ldb8(qb + (t0 + ti * 16 + col) * kD + quad * 8);
    qf[ti][1] = ldb8(qb + (t0 + ti * 16 + col) * kD + 32 + quad * 8);
  }
  u16x8 ones_u;
#pragma unroll
  for (int i = 0; i < 8; ++i) ones_u[i] = 0x3f80;  // bf16 1.0
  const bf16x8 onesf = *reinterpret_cast<bf16x8*>(&ones_u);
  f32x4 oacc[4][4];
  f32x4 lacc[4];
#pragma unroll
  for (int ti = 0; ti < 4; ++ti) {
    lacc[ti] = f32x4{0, 0, 0, 0};
#pragma unroll
    for (int ct = 0; ct < 4; ++ct) oacc[ti][ct] = f32x4{0, 0, 0, 0};
  }
  __shared__ __align__(16) u16 pbuf[4][4][16][36];  // 18432 B
  const int s_beg = z * (kN / kSplit);

  for (int ii = 0; ii < kN / kSplit; ii += 32) {
    const int s0 = s_beg + ii;
    const u16* kr = kb + s0 * kD + quad * 8;
    const bf16x8 k00 = ldb8(kr + col * kD);
    const bf16x8 k01 = ldb8(kr + col * kD + 32);
    const bf16x8 k10 = ldb8(kr + (col + 16) * kD);
    const bf16x8 k11 = ldb8(kr + (col + 16) * kD + 32);
    const u16* vr = vb + s0 + quad * 8;
    bf16x8 vf[4];
#pragma unroll
    for (int ct = 0; ct < 4; ++ct) vf[ct] = ldb8(vr + (ct * 16 + col) * kN);
    u16(*pw)[16][36] = pbuf[w];
#pragma unroll
    for (int ti = 0; ti < 4; ++ti) {
      f32x4 sa0 = {0, 0, 0, 0}, sa1 = {0, 0, 0, 0};
      sa0 = MFMA16x16x32(qf[ti][0], k00, sa0);
      sa0 = MFMA16x16x32(qf[ti][1], k01, sa0);
      sa1 = MFMA16x16x32(qf[ti][0], k10, sa1);
      sa1 = MFMA16x16x32(qf[ti][1], k11, sa1);
#pragma unroll
      for (int r = 0; r < 4; ++r) {
        pw[ti][quad * 4 + r][col] = f2bf(__expf(sa0[r]));
        pw[ti][quad * 4 + r][col + 16] = f2bf(__expf(sa1[r]));
      }
    }
    // wave-private LDS region: drain writes, then read A-layout fragments.
    // DS is in-order per wave, so next-iter writes cannot bypass these reads.
    asm volatile("s_waitcnt lgkmcnt(0)" ::: "memory");
#pragma unroll
    for (int ti = 0; ti < 4; ++ti) {
      const bf16x8 pf = ldb8(&pw[ti][col][quad * 8]);
#pragma unroll
      for (int ct = 0; ct < 4; ++ct)
        oacc[ti][ct] = MFMA16x16x32(pf, vf[ct], oacc[ti][ct]);
      lacc[ti] = MFMA16x16x32(pf, onesf, lacc[ti]);
    }
  }
  float* po = pO + (size_t)(z * 16 + bh) * kN * kD;
  float* plp = pl + (size_t)(z * 16 + bh) * kN;
#pragma unroll
  for (int ti = 0; ti < 4; ++ti)
#pragma unroll
    for (int r = 0; r < 4; ++r) {
      const int t = t0 + ti * 16 + quad * 4 + r;
#pragma unroll
      for (int ct = 0; ct < 4; ++ct)
        po[(size_t)t * kD + ct * 16 + col] = oacc[ti][ct][r];
      if (col == 0) plp[t] = lacc[ti][r];
    }
}

// ---------------------------------------------------------------------------
// Combine 8 split partials: O = sum_z O_z / sum_z l_z -> ht[b][t][c] bf16.
// ---------------------------------------------------------------------------
__global__ __launch_bounds__(256) void attn_combine(const float* __restrict__ pO,
                                                    const float* __restrict__ pl,
                                                    u16* __restrict__ ht) {
  const int idx = blockIdx.x * 256 + threadIdx.x;   // 16bh * 4096t * 16chunks
  const int c0 = (idx & 15) * 4;
  const int t = (idx >> 4) & (kN - 1);
  const int bh = idx >> 16;
  f32x4 acc = {0, 0, 0, 0};
  float lsum = 0.f;
#pragma unroll
  for (int z = 0; z < kSplit; ++z) {
    const size_t base = ((size_t)(z * 16 + bh) * kN + t);
    acc += *reinterpret_cast<const f32x4*>(pO + base * kD + c0);
    lsum += pl[base];
  }
  const float inv = 1.f / lsum;
  u16x4 pk;
#pragma unroll
  for (int i = 0; i < 4; ++i) pk[i] = f2bf(acc[i] * inv);
  const int b = bh >> 2, head = bh & 3;
  *reinterpret_cast<u16x4*>(ht + (size_t)b * (kN * kC) + (size_t)t * kC +
                            head * kD + c0) = pk;
}

// ---------------------------------------------------------------------------
// Proj GEMM + bias + residual: out fp32 (B,C,H,W). Validated r6.
// ---------------------------------------------------------------------------
__global__ __launch_bounds__(256) void proj_kernel(const u16* __restrict__ projw,
                                                   const float* __restrict__ projb,
                                                   const u16* __restrict__ ht,
                                                   const float* __restrict__ x,
                                                   float* __restrict__ out) {
  const int nblk = blockIdx.x, mblk = blockIdx.y, b = blockIdx.z;
  const int tid = threadIdx.x;
  const int w = tid >> 6, l = tid & 63, quad = l >> 4, col = l & 15;
  const int m0 = mblk * 64 + w * 16;
  const int n0 = nblk * 64;
  const u16* hb = ht + b * (kN * kC);
  f32x4 acc[4] = {{0,0,0,0},{0,0,0,0},{0,0,0,0},{0,0,0,0}};
  const u16* ap = projw + (m0 + col) * kC + quad * 8;
  const u16* bp = hb + (n0 + col) * kC + quad * 8;
#pragma unroll
  for (int ks = 0; ks < 8; ++ks) {
    const bf16x8 af = ldb8(ap + ks * 32);
#pragma unroll
    for (int nt = 0; nt < 4; ++nt) {
      const bf16x8 bfr = ldb8(bp + nt * (16 * kC) + ks * 32);
      acc[nt] = MFMA16x16x32(af, bfr, acc[nt]);
    }
  }
#pragma unroll
  for (int nt = 0; nt < 4; ++nt) {
    const int t = n0 + nt * 16 + col;
#pragma unroll
    for (int r = 0; r < 4; ++r) {
      const int o = m0 + quad * 4 + r;
      const int idx = b * (kC * kN) + o * kN + t;
      out[idx] = acc[nt][r] + projb[o] + x[idx];
    }
  }
}

extern "C" void kernel_launch(void* const* d_in, const int* in_sizes, int n_in,
                              void* d_out, int out_size, void* d_ws, size_t ws_size,
                              hipStream_t stream) {
  const float* x = (const float*)d_in[0];
  const float* gnw = (const float*)d_in[1];
  const float* gnb = (const float*)d_in[2];
  const float* qkvw_f = (const float*)d_in[3];
  const float* qkvb = (const float*)d_in[4];
  const float* projw_f = (const float*)d_in[5];
  const float* projb = (const float*)d_in[6];
  float* out = (float*)d_out;

  char* ws = (char*)d_ws;
  u16* xnT = (u16*)(ws);                      // 8 MiB
  u16* qt = (u16*)(ws + (8u << 20));          // 8 MiB
  u16* kt = (u16*)(ws + (16u << 20));         // 8 MiB
  u16* vv = (u16*)(ws + (24u << 20));         // 8 MiB
  u16* ht = (u16*)(ws + (32u << 20));         // 8 MiB
  u16* qkvw = (u16*)(ws + (40u << 20));       // 384 KiB
  u16* projw = (u16*)(ws + (41u << 20));      // 128 KiB
  float* pO = (float*)(ws + (48u << 20));     // 128 MiB (8 splits)
  float* pl = (float*)(ws + (176u << 20));    // 2 MiB

  convert_bf16<<<dim3(192), dim3(256), 0, stream>>>(qkvw_f, qkvw, 768 * kC);
  convert_bf16<<<dim3(64), dim3(256), 0, stream>>>(projw_f, projw, kC * kC);
  gn_kernel<<<dim3(32, 4), dim3(1024), 0, stream>>>(x, gnw, gnb, xnT);
  qkv_gemm<<<dim3(64, 12, 4), dim3(256), 0, stream>>>(qkvw, qkvb, xnT, qt, kt, vv);
  attn_split<<<dim3(16, 16, kSplit), dim3(256), 0, stream>>>(qt, kt, vv, pO, pl);
  attn_combine<<<dim3(4096), dim3(256), 0, stream>>>(pO, pl, ht);
  proj_kernel<<<dim3(64, 4, 4), dim3(256), 0, stream>>>(projw, projb, ht, x, out);
}

// Round 14
// 308.818 us; speedup vs baseline: 1.3545x; 1.0533x over previous
//
#include <hip/hip_runtime.h>

typedef unsigned short u16;
typedef unsigned int u32;
typedef __bf16 bf16x8 __attribute__((ext_vector_type(8)));
typedef float f32x4 __attribute__((ext_vector_type(4)));
typedef u16 u16x4 __attribute__((ext_vector_type(4)));
typedef u16 u16x8 __attribute__((ext_vector_type(8)));

#define MFMA16x16x32(a, b, c) __builtin_amdgcn_mfma_f32_16x16x32_bf16((a), (b), (c), 0, 0, 0)

static constexpr int kB = 4;
static constexpr int kC = 256;
static constexpr int kN = 4096;     // H*W
static constexpr int kHeads = 4;    // per batch
static constexpr int kD = 64;       // head dim
static constexpr int kSplit = 4;    // attn is reg-capped, not grid-capped; 4 halves combine traffic
static constexpr float kScale = 0.35355339059327373f;  // 64^-0.25

__device__ __forceinline__ u16 f2bf(float f) {
  union { float f; u32 i; } v; v.f = f;
  return (u16)((v.i + 0x7fffu + ((v.i >> 16) & 1u)) >> 16);
}
__device__ __forceinline__ bf16x8 ldb8(const u16* p) {
  return *reinterpret_cast<const bf16x8*>(p);
}

// ---------------------------------------------------------------------------
// fp32 -> bf16 weight conversion (grid-stride).
// ---------------------------------------------------------------------------
__global__ void convert_bf16(const float* __restrict__ in, u16* __restrict__ out,
                             int n) {
  for (int i = blockIdx.x * blockDim.x + threadIdx.x; i < n;
       i += gridDim.x * blockDim.x)
    out[i] = f2bf(in[i]);
}

// ---------------------------------------------------------------------------
// GroupNorm (validated r4). Writes bf16 transposed xnT[b][t][c].
// ---------------------------------------------------------------------------
__global__ __launch_bounds__(1024) void gn_kernel(const float* __restrict__ x,
                                                  const float* __restrict__ gnw,
                                                  const float* __restrict__ gnb,
                                                  u16* __restrict__ xnT) {
  const int g = blockIdx.x, b = blockIdx.y;
  const int tid = threadIdx.x;
  const float* xb = x + b * (kC * kN) + g * 8 * kN;
  float vals[4][8];
  float s = 0.f, ss = 0.f;
#pragma unroll
  for (int kk = 0; kk < 4; ++kk) {
    const int t = tid + kk * 1024;
#pragma unroll
    for (int c = 0; c < 8; ++c) {
      const float v_ = xb[c * kN + t];
      vals[kk][c] = v_;
      s += v_; ss += v_ * v_;
    }
  }
#pragma unroll
  for (int off = 32; off > 0; off >>= 1) {
    s += __shfl_down(s, off);
    ss += __shfl_down(ss, off);
  }
  __shared__ float rbuf[32];
  const int wid = tid >> 6, lane = tid & 63;
  if (lane == 0) { rbuf[wid] = s; rbuf[16 + wid] = ss; }
  __syncthreads();
  if (tid < 64) {
    float s2 = (lane < 16) ? rbuf[lane] : 0.f;
    float ss2 = (lane < 16) ? rbuf[16 + lane] : 0.f;
#pragma unroll
    for (int off = 8; off > 0; off >>= 1) {
      s2 += __shfl_down(s2, off);
      ss2 += __shfl_down(ss2, off);
    }
    if (lane == 0) { rbuf[0] = s2; rbuf[1] = ss2; }
  }
  __syncthreads();
  const float inv_n = 1.f / 32768.f;
  const float mu = rbuf[0] * inv_n;
  const float var = rbuf[1] * inv_n - mu * mu;
  const float rs = rsqrtf(var + 1e-5f);
  float wv[8], bv[8];
#pragma unroll
  for (int c = 0; c < 8; ++c) {
    const float wgt = gnw[g * 8 + c] * rs;
    wv[c] = wgt;
    bv[c] = gnb[g * 8 + c] - mu * wgt;
  }
  u16* ob = xnT + b * (kN * kC) + g * 8;
#pragma unroll
  for (int kk = 0; kk < 4; ++kk) {
    const int t = tid + kk * 1024;
    u16x8 pk;
#pragma unroll
    for (int c = 0; c < 8; ++c) pk[c] = f2bf(vals[kk][c] * wv[c] + bv[c]);
    *reinterpret_cast<u16x8*>(ob + t * kC) = pk;
  }
}

// ---------------------------------------------------------------------------
// QKV GEMM (validated r4). Epilogue: qT/kT[bh][t][64] pre-scaled.
// r14: V stored PERMUTED within each 32-column block: stored index
// 2c <-> s=c, 2c+1 <-> s=c+16. Matches attn's packed-P LDS ordering
// (MFMA k-order is summation order -> exact as long as P and V agree).
// ---------------------------------------------------------------------------
__global__ __launch_bounds__(256) void qkv_gemm(const u16* __restrict__ qkvw,
                                                const float* __restrict__ qkvb,
                                                const u16* __restrict__ xnT,
                                                u16* __restrict__ qt,
                                                u16* __restrict__ kt,
                                                u16* __restrict__ vv) {
  const int nblk = blockIdx.x, mblk = blockIdx.y, b = blockIdx.z;
  const int tid = threadIdx.x;
  const int w = tid >> 6, l = tid & 63, quad = l >> 4, col = l & 15;
  const int m0 = mblk * 64 + w * 16;
  const int n0 = nblk * 64;
  const u16* xb = xnT + b * (kN * kC);
  f32x4 acc[4] = {{0,0,0,0},{0,0,0,0},{0,0,0,0},{0,0,0,0}};
  const u16* ap = qkvw + (m0 + col) * kC + quad * 8;
  const u16* bp = xb + (n0 + col) * kC + quad * 8;
#pragma unroll
  for (int ks = 0; ks < 8; ++ks) {
    const bf16x8 af = ldb8(ap + ks * 32);
#pragma unroll
    for (int nt = 0; nt < 4; ++nt) {
      const bf16x8 bfr = ldb8(bp + nt * (16 * kC) + ks * 32);
      acc[nt] = MFMA16x16x32(af, bfr, acc[nt]);
    }
  }
  const int o_base = m0 + quad * 4;
  const int head = o_base / 192;
  const int rr = o_base % 192;
  const int bh = b * kHeads + head;
  const int seg = rr >> 6;
  const int c0 = rr & 63;
  float bias[4];
#pragma unroll
  for (int r = 0; r < 4; ++r) bias[r] = qkvb[o_base + r];
#pragma unroll
  for (int nt = 0; nt < 4; ++nt) {
    const int t = n0 + nt * 16 + col;
    if (seg == 2) {
      // permuted position within the 32-block (see header comment)
      const int tp = n0 + (nt >> 1) * 32 + 2 * col + (nt & 1);
#pragma unroll
      for (int r = 0; r < 4; ++r)
        vv[bh * (kD * kN) + (c0 + r) * kN + tp] = f2bf(acc[nt][r] + bias[r]);
    } else {
      u16* dst = (seg == 0 ? qt : kt) + bh * (kN * kD) + t * kD + c0;
      u16x4 pk;
#pragma unroll
      for (int r = 0; r < 4; ++r) pk[r] = f2bf((acc[nt][r] + bias[r]) * kScale);
      *reinterpret_cast<u16x4*>(dst) = pk;
    }
  }
}

// ---------------------------------------------------------------------------
// Flash attention, linear split form, 64 Q-rows/wave (4 Q-tiles).
// r14: P written to LDS as u32 pairs (p_c, p_{c+16}) via one v_perm_b32
// (RTZ bf16) -> 16 ds_write_b32 + 16 perms per iter instead of
// 32 ds_write_b16 + ~160 VALU ops. s-order permutation matches vv layout.
// launch_bounds(256,2): ~164 unified regs (80 acc) -> 3 waves/SIMD, no spill.
// ---------------------------------------------------------------------------
__global__ __launch_bounds__(256, 2) void attn_split(const u16* __restrict__ qt,
                                                     const u16* __restrict__ kt,
                                                     const u16* __restrict__ vv,
                                                     float* __restrict__ pO,
                                                     float* __restrict__ pl) {
  const int tblk = blockIdx.x, bh = blockIdx.y, z = blockIdx.z;
  const int tid = threadIdx.x;
  const int w = tid >> 6, l = tid & 63, quad = l >> 4, col = l & 15;
  const int t0 = tblk * 256 + w * 64;
  const u16* qb = qt + bh * (kN * kD);
  const u16* kb = kt + bh * (kN * kD);
  const u16* vb = vv + bh * (kD * kN);
  bf16x8 qf[4][2];
#pragma unroll
  for (int ti = 0; ti < 4; ++ti) {
    qf[ti][0] = ldb8(qb + (t0 + ti * 16 + col) * kD + quad * 8);
    qf[ti][1] = ldb8(qb + (t0 + ti * 16 + col) * kD + 32 + quad * 8);
  }
  u16x8 ones_u;
#pragma unroll
  for (int i = 0; i < 8; ++i) ones_u[i] = 0x3f80;  // bf16 1.0
  const bf16x8 onesf = *reinterpret_cast<bf16x8*>(&ones_u);
  f32x4 oacc[4][4];
  f32x4 lacc[4];
#pragma unroll
  for (int ti = 0; ti < 4; ++ti) {
    lacc[ti] = f32x4{0, 0, 0, 0};
#pragma unroll
    for (int ct = 0; ct < 4; ++ct) oacc[ti][ct] = f32x4{0, 0, 0, 0};
  }
  __shared__ __align__(16) u16 pbuf[4][4][16][36];  // 18432 B, row stride 72 B
  const int s_beg = z * (kN / kSplit);

  for (int ii = 0; ii < kN / kSplit; ii += 32) {
    const int s0 = s_beg + ii;
    const u16* kr = kb + s0 * kD + quad * 8;
    const bf16x8 k00 = ldb8(kr + col * kD);
    const bf16x8 k01 = ldb8(kr + col * kD + 32);
    const bf16x8 k10 = ldb8(kr + (col + 16) * kD);
    const bf16x8 k11 = ldb8(kr + (col + 16) * kD + 32);
    const u16* vr = vb + s0 + quad * 8;
    bf16x8 vf[4];
#pragma unroll
    for (int ct = 0; ct < 4; ++ct) vf[ct] = ldb8(vr + (ct * 16 + col) * kN);
    u16(*pw)[16][36] = pbuf[w];
#pragma unroll
    for (int ti = 0; ti < 4; ++ti) {
      f32x4 sa0 = {0, 0, 0, 0}, sa1 = {0, 0, 0, 0};
      sa0 = MFMA16x16x32(qf[ti][0], k00, sa0);
      sa0 = MFMA16x16x32(qf[ti][1], k01, sa0);
      sa1 = MFMA16x16x32(qf[ti][0], k10, sa1);
      sa1 = MFMA16x16x32(qf[ti][1], k11, sa1);
#pragma unroll
      for (int r = 0; r < 4; ++r) {
        const u32 e0 = __float_as_uint(__expf(sa0[r]));
        const u32 e1 = __float_as_uint(__expf(sa1[r]));
        // one v_perm: low16 = bf16_rtz(e0) [s=col], high16 = bf16_rtz(e1) [s=col+16]
        const u32 pk = __builtin_amdgcn_perm(e1, e0, 0x07060302u);
        *reinterpret_cast<u32*>(&pw[ti][quad * 4 + r][2 * col]) = pk;
      }
    }
    // wave-private LDS region: drain writes, then read A-layout fragments.
    // DS is in-order per wave, so next-iter writes cannot bypass these reads.
    asm volatile("s_waitcnt lgkmcnt(0)" ::: "memory");
#pragma unroll
    for (int ti = 0; ti < 4; ++ti) {
      const bf16x8 pf = ldb8(&pw[ti][col][quad * 8]);
#pragma unroll
      for (int ct = 0; ct < 4; ++ct)
        oacc[ti][ct] = MFMA16x16x32(pf, vf[ct], oacc[ti][ct]);
      lacc[ti] = MFMA16x16x32(pf, onesf, lacc[ti]);
    }
  }
  float* po = pO + (size_t)(z * 16 + bh) * kN * kD;
  float* plp = pl + (size_t)(z * 16 + bh) * kN;
#pragma unroll
  for (int ti = 0; ti < 4; ++ti)
#pragma unroll
    for (int r = 0; r < 4; ++r) {
      const int t = t0 + ti * 16 + quad * 4 + r;
#pragma unroll
      for (int ct = 0; ct < 4; ++ct)
        po[(size_t)t * kD + ct * 16 + col] = oacc[ti][ct][r];
      if (col == 0) plp[t] = lacc[ti][r];
    }
}

// ---------------------------------------------------------------------------
// Combine 4 split partials: O = sum_z O_z / sum_z l_z -> ht[b][t][c] bf16.
// ---------------------------------------------------------------------------
__global__ __launch_bounds__(256) void attn_combine(const float* __restrict__ pO,
                                                    const float* __restrict__ pl,
                                                    u16* __restrict__ ht) {
  const int idx = blockIdx.x * 256 + threadIdx.x;   // 16bh * 4096t * 16chunks
  const int c0 = (idx & 15) * 4;
  const int t = (idx >> 4) & (kN - 1);
  const int bh = idx >> 16;
  f32x4 acc = {0, 0, 0, 0};
  float lsum = 0.f;
#pragma unroll
  for (int z = 0; z < kSplit; ++z) {
    const size_t base = ((size_t)(z * 16 + bh) * kN + t);
    acc += *reinterpret_cast<const f32x4*>(pO + base * kD + c0);
    lsum += pl[base];
  }
  const float inv = 1.f / lsum;
  u16x4 pk;
#pragma unroll
  for (int i = 0; i < 4; ++i) pk[i] = f2bf(acc[i] * inv);
  const int b = bh >> 2, head = bh & 3;
  *reinterpret_cast<u16x4*>(ht + (size_t)b * (kN * kC) + (size_t)t * kC +
                            head * kD + c0) = pk;
}

// ---------------------------------------------------------------------------
// Proj GEMM + bias + residual: out fp32 (B,C,H,W). Validated r6.
// ---------------------------------------------------------------------------
__global__ __launch_bounds__(256) void proj_kernel(const u16* __restrict__ projw,
                                                   const float* __restrict__ projb,
                                                   const u16* __restrict__ ht,
                                                   const float* __restrict__ x,
                                                   float* __restrict__ out) {
  const int nblk = blockIdx.x, mblk = blockIdx.y, b = blockIdx.z;
  const int tid = threadIdx.x;
  const int w = tid >> 6, l = tid & 63, quad = l >> 4, col = l & 15;
  const int m0 = mblk * 64 + w * 16;
  const int n0 = nblk * 64;
  const u16* hb = ht + b * (kN * kC);
  f32x4 acc[4] = {{0,0,0,0},{0,0,0,0},{0,0,0,0},{0,0,0,0}};
  const u16* ap = projw + (m0 + col) * kC + quad * 8;
  const u16* bp = hb + (n0 + col) * kC + quad * 8;
#pragma unroll
  for (int ks = 0; ks < 8; ++ks) {
    const bf16x8 af = ldb8(ap + ks * 32);
#pragma unroll
    for (int nt = 0; nt < 4; ++nt) {
      const bf16x8 bfr = ldb8(bp + nt * (16 * kC) + ks * 32);
      acc[nt] = MFMA16x16x32(af, bfr, acc[nt]);
    }
  }
#pragma unroll
  for (int nt = 0; nt < 4; ++nt) {
    const int t = n0 + nt * 16 + col;
#pragma unroll
    for (int r = 0; r < 4; ++r) {
      const int o = m0 + quad * 4 + r;
      const int idx = b * (kC * kN) + o * kN + t;
      out[idx] = acc[nt][r] + projb[o] + x[idx];
    }
  }
}

extern "C" void kernel_launch(void* const* d_in, const int* in_sizes, int n_in,
                              void* d_out, int out_size, void* d_ws, size_t ws_size,
                              hipStream_t stream) {
  const float* x = (const float*)d_in[0];
  const float* gnw = (const float*)d_in[1];
  const float* gnb = (const float*)d_in[2];
  const float* qkvw_f = (const float*)d_in[3];
  const float* qkvb = (const float*)d_in[4];
  const float* projw_f = (const float*)d_in[5];
  const float* projb = (const float*)d_in[6];
  float* out = (float*)d_out;

  char* ws = (char*)d_ws;
  u16* xnT = (u16*)(ws);                      // 8 MiB
  u16* qt = (u16*)(ws + (8u << 20));          // 8 MiB
  u16* kt = (u16*)(ws + (16u << 20));         // 8 MiB
  u16* vv = (u16*)(ws + (24u << 20));         // 8 MiB
  u16* ht = (u16*)(ws + (32u << 20));         // 8 MiB
  u16* qkvw = (u16*)(ws + (40u << 20));       // 384 KiB
  u16* projw = (u16*)(ws + (41u << 20));      // 128 KiB
  float* pO = (float*)(ws + (48u << 20));     // 64 MiB (4 splits)
  float* pl = (float*)(ws + (112u << 20));    // 1 MiB

  convert_bf16<<<dim3(192), dim3(256), 0, stream>>>(qkvw_f, qkvw, 768 * kC);
  convert_bf16<<<dim3(64), dim3(256), 0, stream>>>(projw_f, projw, kC * kC);
  gn_kernel<<<dim3(32, 4), dim3(1024), 0, stream>>>(x, gnw, gnb, xnT);
  qkv_gemm<<<dim3(64, 12, 4), dim3(256), 0, stream>>>(qkvw, qkvb, xnT, qt, kt, vv);
  attn_split<<<dim3(16, 16, kSplit), dim3(256), 0, stream>>>(qt, kt, vv, pO, pl);
  attn_combine<<<dim3(4096), dim3(256), 0, stream>>>(pO, pl, ht);
  proj_kernel<<<dim3(64, 4, 4), dim3(256), 0, stream>>>(projw, projb, ht, x, out);
}